// Round 6
// baseline (65.136 us; speedup 1.0000x reference)
//
#include <hip/hip_runtime.h>

// RegionLoss v6: 1 cell/thread.
//  - max TLP: 3610 blocks, LDS = 19.9KB -> 8 blocks/CU = 32 waves/CU
//  - max MLP: target via async global_load_lds; 32 channel loads pinned in
//    VGPRs with asm keep-alive so they issue back-to-back (no sinking)
// output: (nB, NA*32, nH, nW) f32 ; target: (nB, NA, nH, nW, 19) f32

namespace {

constexpr int kNC = 13;
constexpr int kCh = 32;                  // 19 + kNC channels per anchor
constexpr int kH = 76, kW = 76;
constexpr int kSP = kH * kW;             // 5776
constexpr int kCells = 32 * 5 * kSP;     // 924160
constexpr int kBlocks = kCells / 256;    // 3610 (exact)
constexpr int kTW = 256 * 19;            // 4864 target words per block

__device__ __forceinline__ void gl4(const float* g, float* l) {
  __builtin_amdgcn_global_load_lds(
      (const __attribute__((address_space(1))) void*)g,
      (__attribute__((address_space(3))) void*)l, 4, 0, 0);
}
__device__ __forceinline__ void gl16(const float* g, float* l) {
  __builtin_amdgcn_global_load_lds(
      (const __attribute__((address_space(1))) void*)g,
      (__attribute__((address_space(3))) void*)l, 16, 0, 0);
}

__global__ __launch_bounds__(256, 6)
void region_loss_v6(const float* __restrict__ out,
                    const float* __restrict__ tgt,
                    double* __restrict__ acc)
{
  __shared__ __align__(16) float tl[kTW];        // 19456 B
  __shared__ float wsum[4];

  const int tid  = threadIdx.x;
  const int blk  = blockIdx.x;
  const int lane = tid & 63;
  const int w    = tid >> 6;

  // ---- async stage: this block's target slab (7 instrs/wave, 0 VGPR) ----
  const float* tgw = tgt + (size_t)blk * kTW + w * 1216;
  float* tlw = &tl[w * 1216];
#pragma unroll
  for (int k = 0; k < 4; ++k)
    gl16(tgw + k * 256 + lane * 4, tlw + k * 256);
#pragma unroll
  for (int r = 0; r < 3; ++r)
    gl4(tgw + 1024 + r * 64 + lane, tlw + 1024 + r * 64);

  // ---- 32 channel loads into registers, pinned (issue back-to-back) ----
  const int n = blk * 256 + tid;
  const int q = n / kSP;                         // b*NA + a
  const int s = n - q * kSP;
  const float* op = out + (size_t)q * kCh * kSP + s;

  float chv[kCh];
#pragma unroll
  for (int c = 0; c < kCh; ++c) chv[c] = op[(size_t)c * kSP];
#pragma unroll
  for (int c = 0; c < kCh; ++c) asm volatile("" : "+v"(chv[c]));

  __syncthreads();                               // drain + slab visible

  // ---- per-cell loss ----
  const int hh = s / kW;
  const float fh = (float)hh;
  const float fw = (float)(s - hh * kW);

  const int rb = tid * 19;                       // stride 19: conflict-free
  const float clsf = tl[rb];
  const bool obj = (clsf != 0.f);

  float tcf = 0.f, lcd = 0.f;
#pragma unroll
  for (int i = 0; i < 9; ++i) {
    float xv = chv[14 + 2 * i];
    float yv = chv[15 + 2 * i];
    if (i == 0) {
      xv = __builtin_amdgcn_rcpf(1.f + __expf(-xv));
      yv = __builtin_amdgcn_rcpf(1.f + __expf(-yv));
    }
    const float gx = tl[rb + 1 + 2 * i];
    const float gy = tl[rb + 2 + 2 * i];
    const float tx = gx - fw;
    const float ty = gy - fh;
    const float dx = tx - (xv + fw);
    const float dy = ty - (yv + fh);
    const float dt = sqrtf(dx * dx + dy * dy);
    if (dt < 30.f) tcf += __expf(2.f - dt * (1.f / 15.f));
    const float ex = xv - tx;
    const float ey = yv - ty;
    lcd += ex * ex + ey * ey;
  }

  const float d = chv[kNC] - tcf * (1.f / 9.f);
  float loss = 0.005f * d * d;                   // 0.5*(0.1*(conf-tconf))^2
  if (obj) loss += 0.5f * lcd;

  if (obj) {
    float mx = chv[0];
#pragma unroll
    for (int c = 1; c < kNC; ++c) mx = fmaxf(mx, chv[c]);
    float se = 0.f;
#pragma unroll
    for (int c = 0; c < kNC; ++c) se += __expf(chv[c] - mx);
    const int tc = (int)clsf;
    float sel = 0.f;
#pragma unroll
    for (int c = 0; c < kNC; ++c) sel += (c == tc) ? chv[c] : 0.f;
    loss += -(sel - mx - __logf(se));
  }

  // ---- reduce: wave(64) shuffle -> LDS -> one double atomic per block ----
#pragma unroll
  for (int off = 32; off > 0; off >>= 1)
    loss += __shfl_down(loss, off, 64);

  if (lane == 0) wsum[w] = loss;
  __syncthreads();
  if (tid == 0)
    atomicAdd(acc, (double)(wsum[0] + wsum[1] + wsum[2] + wsum[3]));
}

__global__ void finalize_kernel(const double* __restrict__ acc,
                                float* __restrict__ outv)
{
  outv[0] = (float)acc[0];
}

}  // namespace

extern "C" void kernel_launch(void* const* d_in, const int* in_sizes, int n_in,
                              void* d_out, int out_size, void* d_ws, size_t ws_size,
                              hipStream_t stream) {
  const float* output = (const float*)d_in[0];
  const float* target = (const float*)d_in[1];
  double* acc = (double*)d_ws;

  hipMemsetAsync(acc, 0, sizeof(double), stream);

  region_loss_v6<<<kBlocks, 256, 0, stream>>>(output, target, acc);
  finalize_kernel<<<1, 1, 0, stream>>>(acc, (float*)d_out);
}

// Round 7
// 47.411 us; speedup vs baseline: 1.3739x; 1.3739x over previous
//
#include <hip/hip_runtime.h>

// RegionLoss v7 = v4 structure with guaranteed load batching:
//  - 2 cells/thread, float2 channel loads (8B/lane coalescing sweet spot)
//  - all 32 channel loads issued, then pinned by TWO asm statements
//    (16 float2 operands each) -> >=16-deep MLP, no per-load serialization
//  - target slab staged via global_load_lds width16 (zero VGPR, async)
// output: (nB, NA*32, nH, nW) f32 ; target: (nB, NA, nH, nW, 19) f32

namespace {

constexpr int kNC = 13;
constexpr int kCh = 32;                    // 19 + kNC channels per anchor
constexpr int kH = 76, kW = 76;
constexpr int kSP = kH * kW;               // 5776 (even)
constexpr int kCells = 32 * 5 * kSP;       // 924160
constexpr int kCPB = 512;                  // cells per block (256 thr x 2)
constexpr int kBlocks = kCells / kCPB;     // 1805 (exact)
constexpr int kTW = kCPB * 19;             // 9728 words = 38912 B
constexpr int kF4PW = (kTW / 4) / 4;       // 608 float4 per wave

typedef float f2 __attribute__((ext_vector_type(2)));

__device__ __forceinline__ void gl16(const float* g, float* l) {
  __builtin_amdgcn_global_load_lds(
      (const __attribute__((address_space(1))) void*)g,
      (__attribute__((address_space(3))) void*)l, 16, 0, 0);
}

__global__ __launch_bounds__(256, 4)
void region_loss_v7(const float* __restrict__ out,
                    const float* __restrict__ tgt,
                    double* __restrict__ acc)
{
  __shared__ __align__(16) float tl[kTW];    // 38912 B
  __shared__ float wsum[4];

  const int tid  = threadIdx.x;
  const int blk  = blockIdx.x;
  const int lane = tid & 63;
  const int w    = tid >> 6;

  // ---- async stage target slab: 9 full + 1 half-wave gl16 per wave ----
  const float* tg = tgt + (size_t)blk * kTW;
  const int b4 = w * kF4PW;                  // this wave's float4 base
#pragma unroll
  for (int k = 0; k < 9; ++k)
    gl16(tg + (size_t)(b4 + k * 64 + lane) * 4, &tl[(size_t)(b4 + k * 64) * 4]);
  if (lane < 32)
    gl16(tg + (size_t)(b4 + 576 + lane) * 4, &tl[(size_t)(b4 + 576) * 4]);

  // ---- 32 channel float2 loads, batched then pinned ----
  const int n0 = blk * kCPB + tid * 2;       // even; pair never crosses q
  const int q  = n0 / kSP;                   // b*NA + a
  const int s0 = n0 - q * kSP;
  const float* op = out + (size_t)q * kCh * kSP + s0;

  f2 ch[kCh];
#pragma unroll
  for (int c = 0; c < kCh; ++c)
    ch[c] = *(const f2*)(op + (size_t)c * kSP);

  asm volatile("" :
      "+v"(ch[0]), "+v"(ch[1]), "+v"(ch[2]), "+v"(ch[3]),
      "+v"(ch[4]), "+v"(ch[5]), "+v"(ch[6]), "+v"(ch[7]),
      "+v"(ch[8]), "+v"(ch[9]), "+v"(ch[10]), "+v"(ch[11]),
      "+v"(ch[12]), "+v"(ch[13]), "+v"(ch[14]), "+v"(ch[15]));
  asm volatile("" :
      "+v"(ch[16]), "+v"(ch[17]), "+v"(ch[18]), "+v"(ch[19]),
      "+v"(ch[20]), "+v"(ch[21]), "+v"(ch[22]), "+v"(ch[23]),
      "+v"(ch[24]), "+v"(ch[25]), "+v"(ch[26]), "+v"(ch[27]),
      "+v"(ch[28]), "+v"(ch[29]), "+v"(ch[30]), "+v"(ch[31]));

  __syncthreads();                           // vmcnt(0) drain + barrier

  // ---- per-cell loss ----
  const int hh = s0 / kW;
  const float fh = (float)hh;
  const float fw0 = (float)(s0 - hh * kW);   // s0 even; s0+1 same row
                                             // (kW=76 even, s0 even -> w<75)
  const int r0 = tid * 38;                   // word offset of first record
  float loss[2] = {0.f, 0.f};

#pragma unroll
  for (int j = 0; j < 2; ++j) {
    const int rb = r0 + j * 19;
    const float fw = fw0 + (float)j;
    const float clsf = tl[rb];
    const bool obj = (clsf != 0.f);

    float tcf = 0.f, lcd = 0.f;
#pragma unroll
    for (int i = 0; i < 9; ++i) {
      float xv = ch[14 + 2 * i][j];
      float yv = ch[15 + 2 * i][j];
      if (i == 0) {
        xv = __builtin_amdgcn_rcpf(1.f + __expf(-xv));
        yv = __builtin_amdgcn_rcpf(1.f + __expf(-yv));
      }
      const float gx = tl[rb + 1 + 2 * i];
      const float gy = tl[rb + 2 + 2 * i];
      const float tx = gx - fw;
      const float ty = gy - fh;
      const float dx = tx - (xv + fw);
      const float dy = ty - (yv + fh);
      const float dt = sqrtf(dx * dx + dy * dy);
      if (dt < 30.f) tcf += __expf(2.f - dt * (1.f / 15.f));
      const float ex = xv - tx;
      const float ey = yv - ty;
      lcd += ex * ex + ey * ey;
    }

    const float d = ch[kNC][j] - tcf * (1.f / 9.f);
    loss[j] = 0.005f * d * d;                // 0.5*(0.1*(conf-tconf))^2
    if (obj) loss[j] += 0.5f * lcd;

    if (obj) {
      float mx = ch[0][j];
#pragma unroll
      for (int c = 1; c < kNC; ++c) mx = fmaxf(mx, ch[c][j]);
      float se = 0.f;
#pragma unroll
      for (int c = 0; c < kNC; ++c) se += __expf(ch[c][j] - mx);
      const int tc = (int)clsf;
      float sel = 0.f;
#pragma unroll
      for (int c = 0; c < kNC; ++c) sel += (c == tc) ? ch[c][j] : 0.f;
      loss[j] += -(sel - mx - __logf(se));
    }
  }

  // ---- reduce: wave(64) shuffle -> LDS -> one double atomic per block ----
  float lsum = loss[0] + loss[1];
#pragma unroll
  for (int off = 32; off > 0; off >>= 1)
    lsum += __shfl_down(lsum, off, 64);

  if (lane == 0) wsum[w] = lsum;
  __syncthreads();
  if (tid == 0)
    atomicAdd(acc, (double)(wsum[0] + wsum[1] + wsum[2] + wsum[3]));
}

__global__ void finalize_kernel(const double* __restrict__ acc,
                                float* __restrict__ outv)
{
  outv[0] = (float)acc[0];
}

}  // namespace

extern "C" void kernel_launch(void* const* d_in, const int* in_sizes, int n_in,
                              void* d_out, int out_size, void* d_ws, size_t ws_size,
                              hipStream_t stream) {
  const float* output = (const float*)d_in[0];
  const float* target = (const float*)d_in[1];
  double* acc = (double*)d_ws;

  hipMemsetAsync(acc, 0, sizeof(double), stream);

  region_loss_v7<<<kBlocks, 256, 0, stream>>>(output, target, acc);
  finalize_kernel<<<1, 1, 0, stream>>>(acc, (float*)d_out);
}

// Round 8
// 41.655 us; speedup vs baseline: 1.5637x; 1.1382x over previous
//
#include <hip/hip_runtime.h>

// RegionLoss v8: max TLP + staged target + batched channel loads.
//  - 512 thr/block, 1 cell/thread: slab 38.9KB serves 8 waves ->
//    4 blocks/CU = 32 waves/CU (100% theoretical occupancy), VGPR<=64
//  - 32 scalar channel loads issued first, then 38 gl16 slab loads,
//    then two 16-op pins (vmcnt(21)/vmcnt(5)), single drain at barrier
//  - block partials -> 64 line-spread double slots (no single-address atomic)

namespace {

constexpr int kNC = 13;
constexpr int kCh = 32;                  // 19 + kNC channels per anchor
constexpr int kH = 76, kW = 76;
constexpr int kSP = kH * kW;             // 5776
constexpr int kCells = 32 * 5 * kSP;     // 924160
constexpr int kTPB = 512;
constexpr int kBlocks = kCells / kTPB;   // 1805 (exact)
constexpr int kTW = kTPB * 19;           // 9728 words = 38912 B
constexpr int kF4 = kTW / 4;             // 2432 float4s = 38 wave-instrs

__device__ __forceinline__ void gl16(const float* g, float* l) {
  __builtin_amdgcn_global_load_lds(
      (const __attribute__((address_space(1))) void*)g,
      (__attribute__((address_space(3))) void*)l, 16, 0, 0);
}

__global__ __launch_bounds__(512, 8)
void region_loss_v8(const float* __restrict__ out,
                    const float* __restrict__ tgt,
                    double* __restrict__ acc)
{
  __shared__ __align__(16) float tl[kTW];    // 38912 B
  __shared__ float wsum[8];

  const int tid  = threadIdx.x;
  const int blk  = blockIdx.x;
  const int lane = tid & 63;
  const int w    = tid >> 6;

  // ---- 32 scalar channel loads issued first (oldest in vmcnt FIFO) ----
  const int n = blk * kTPB + tid;
  const int q = n / kSP;                     // b*NA + a
  const int s = n - q * kSP;
  const float* op = out + (size_t)q * kCh * kSP + s;

  float ch[kCh];
#pragma unroll
  for (int c = 0; c < kCh; ++c) ch[c] = op[(size_t)c * kSP];

  // ---- async stage target slab: 38 x 1KB wave-instrs across 8 waves ----
  const float* tg = tgt + (size_t)blk * kTW;
#pragma unroll
  for (int k = 0; k < 5; ++k) {
    const int i4 = (k * 8 + w) * 64;         // wave-uniform float4 base
    if (i4 < kF4)
      gl16(tg + (size_t)(i4 + lane) * 4, &tl[(size_t)i4 * 4]);
  }

  // ---- pin channel values: force "loaded before barrier", batched waits ----
  asm volatile("" :
      "+v"(ch[0]), "+v"(ch[1]), "+v"(ch[2]), "+v"(ch[3]),
      "+v"(ch[4]), "+v"(ch[5]), "+v"(ch[6]), "+v"(ch[7]),
      "+v"(ch[8]), "+v"(ch[9]), "+v"(ch[10]), "+v"(ch[11]),
      "+v"(ch[12]), "+v"(ch[13]), "+v"(ch[14]), "+v"(ch[15]));
  asm volatile("" :
      "+v"(ch[16]), "+v"(ch[17]), "+v"(ch[18]), "+v"(ch[19]),
      "+v"(ch[20]), "+v"(ch[21]), "+v"(ch[22]), "+v"(ch[23]),
      "+v"(ch[24]), "+v"(ch[25]), "+v"(ch[26]), "+v"(ch[27]),
      "+v"(ch[28]), "+v"(ch[29]), "+v"(ch[30]), "+v"(ch[31]));

  __syncthreads();                           // drain + slab visible

  // ---- per-cell loss ----
  const int hh = s / kW;
  const float fh = (float)hh;
  const float fw = (float)(s - hh * kW);

  const int rb = tid * 19;                   // stride-19: 2-way (free)
  const float clsf = tl[rb];
  const bool obj = (clsf != 0.f);

  float tcf = 0.f, lcd = 0.f;
#pragma unroll
  for (int i = 0; i < 9; ++i) {
    float xv = ch[14 + 2 * i];
    float yv = ch[15 + 2 * i];
    if (i == 0) {
      xv = __builtin_amdgcn_rcpf(1.f + __expf(-xv));
      yv = __builtin_amdgcn_rcpf(1.f + __expf(-yv));
    }
    const float gx = tl[rb + 1 + 2 * i];
    const float gy = tl[rb + 2 + 2 * i];
    const float tx = gx - fw;
    const float ty = gy - fh;
    const float dx = tx - (xv + fw);
    const float dy = ty - (yv + fh);
    const float dt = sqrtf(dx * dx + dy * dy);
    if (dt < 30.f) tcf += __expf(2.f - dt * (1.f / 15.f));
    const float ex = xv - tx;
    const float ey = yv - ty;
    lcd += ex * ex + ey * ey;
  }

  const float d = ch[kNC] - tcf * (1.f / 9.f);
  float loss = 0.005f * d * d;               // 0.5*(0.1*(conf-tconf))^2
  if (obj) loss += 0.5f * lcd;

  if (obj) {
    float mx = ch[0];
#pragma unroll
    for (int c = 1; c < kNC; ++c) mx = fmaxf(mx, ch[c]);
    float se = 0.f;
#pragma unroll
    for (int c = 0; c < kNC; ++c) se += __expf(ch[c] - mx);
    const int tc = (int)clsf;
    float sel = 0.f;
#pragma unroll
    for (int c = 0; c < kNC; ++c) sel += (c == tc) ? ch[c] : 0.f;
    loss += -(sel - mx - __logf(se));
  }

  // ---- reduce: wave shuffle -> LDS -> one atomic/block to spread slot ----
#pragma unroll
  for (int off = 32; off > 0; off >>= 1)
    loss += __shfl_down(loss, off, 64);

  if (lane == 0) wsum[w] = loss;
  __syncthreads();
  if (tid == 0) {
    float b = 0.f;
#pragma unroll
    for (int i = 0; i < 8; ++i) b += wsum[i];
    atomicAdd(&acc[(blk & 63) * 8], (double)b);   // 64 line-spread slots
  }
}

__global__ void finalize_kernel(const double* __restrict__ acc,
                                float* __restrict__ outv)
{
  const int lane = threadIdx.x;
  double v = acc[lane * 8];
#pragma unroll
  for (int off = 32; off > 0; off >>= 1)
    v += __shfl_down(v, off, 64);
  if (lane == 0) outv[0] = (float)v;
}

}  // namespace

extern "C" void kernel_launch(void* const* d_in, const int* in_sizes, int n_in,
                              void* d_out, int out_size, void* d_ws, size_t ws_size,
                              hipStream_t stream) {
  const float* output = (const float*)d_in[0];
  const float* target = (const float*)d_in[1];
  double* acc = (double*)d_ws;

  hipMemsetAsync(acc, 0, 64 * 8 * sizeof(double), stream);

  region_loss_v8<<<kBlocks, kTPB, 0, stream>>>(output, target, acc);
  finalize_kernel<<<1, 64, 0, stream>>>(acc, (float*)d_out);
}